// Round 9
// baseline (630.210 us; speedup 1.0000x reference)
//
#include <hip/hip_runtime.h>
#include <hip/hip_bf16.h>

// ---------------------------------------------------------------------------
// GCN via device-built CSR (no f32 atomics), all inter-kernel tensors bf16:
//   mega0 = [deg count | gemm1 30%]   mega1 = [CSR fill | gemm1 70%]
//   3x [ hw = bf16(hprev @ W) ;
//        hcat_k[n] = bf16(relu(dinv_n*(dinv_n*hw[n] + sum_in dinv_r*hw[r])+b)) ]
//   out = hcat @ Wlin + blin   (f32 out)
// k_agg: 16 lanes/node x ushort8 -> 4 nodes/wave, 8-deep gather unroll.
// GEMMs: K=32 LDS chunks, A-stream reg prefetch, W direct to LDS,
// __launch_bounds__(256,2) = 128-VGPR cap = spill-free (arg>=3 spills).
// ---------------------------------------------------------------------------

__device__ __forceinline__ unsigned short f2bf(float f) {  // RNE f32->bf16
  unsigned int u = __float_as_uint(f);
  u += 0x7FFFu + ((u >> 16) & 1u);
  return (unsigned short)(u >> 16);
}
__device__ __forceinline__ float bf2f(unsigned short h) {
  return __uint_as_float((unsigned int)h << 16);
}
__device__ __forceinline__ unsigned int bfpack(float a, float b) {
  return ((unsigned int)f2bf(a)) | ((unsigned int)f2bf(b) << 16);
}
__device__ __forceinline__ void bf8_unpack(uint4 v, float* f) {
  f[0] = __uint_as_float(v.x << 16); f[1] = __uint_as_float(v.x & 0xFFFF0000u);
  f[2] = __uint_as_float(v.y << 16); f[3] = __uint_as_float(v.y & 0xFFFF0000u);
  f[4] = __uint_as_float(v.z << 16); f[5] = __uint_as_float(v.z & 0xFFFF0000u);
  f[6] = __uint_as_float(v.w << 16); f[7] = __uint_as_float(v.w & 0xFFFF0000u);
}

// ---- GEMM body, f32 A (layer 1: A = x) -> hw bf16 -------------------------
__device__ __forceinline__ void gemm128_f32(
    const float* __restrict__ A, long long lda,
    const float* __restrict__ W, unsigned short* __restrict__ hw, int N, int n0,
    float (*hsT)[128], float (*Ws)[128]) {
  const int tid = threadIdx.x;
  const int rows = min(128, N - n0);
  const int tc4 = (tid & 15) << 2;   // col group 1: tc4..+3; group 2: +64
  const int tr = (tid >> 4) << 3;
  float acc[8][8] = {};
  float4 pa[4];

  auto loadA = [&](int kc) {
    #pragma unroll
    for (int u = 0; u < 4; ++u) {
      const int i = tid + 256 * u;
      const int r = i >> 3, k4 = (i & 7) << 2;
      float4 v = make_float4(0.f, 0.f, 0.f, 0.f);
      if (r < rows) v = *(const float4*)(A + (size_t)(n0 + r) * lda + kc + k4);
      pa[u] = v;
    }
  };
  auto stageA = [&]() {
    #pragma unroll
    for (int u = 0; u < 4; ++u) {
      const int i = tid + 256 * u;
      const int r = i >> 3, k4 = (i & 7) << 2;
      const int c = r ^ k4;
      hsT[k4 + 0][c] = pa[u].x; hsT[k4 + 1][c] = pa[u].y;
      hsT[k4 + 2][c] = pa[u].z; hsT[k4 + 3][c] = pa[u].w;
    }
  };
  auto stageW = [&](int kc) {
    #pragma unroll
    for (int u = 0; u < 4; ++u) {
      const int i = tid + 256 * u;
      const int k = i >> 5, c = (i & 31) << 2;
      *(float4*)&Ws[k][c] = *(const float4*)(W + (size_t)(kc + k) * 128 + c);
    }
  };

  loadA(0);
  for (int kc = 0; kc < 128; kc += 32) {
    stageW(kc);
    stageA();
    __syncthreads();
    if (kc + 32 < 128) loadA(kc + 32);
    #pragma unroll
    for (int k = 0; k < 32; ++k) {
      const int s = k & 28;
      const float4 a0 = *(const float4*)&hsT[k][tr ^ s];
      const float4 a1 = *(const float4*)&hsT[k][(tr + 4) ^ s];
      const float4 w0 = *(const float4*)&Ws[k][tc4];
      const float4 w1 = *(const float4*)&Ws[k][tc4 + 64];
      const float a[8] = {a0.x, a0.y, a0.z, a0.w, a1.x, a1.y, a1.z, a1.w};
      const float w[8] = {w0.x, w0.y, w0.z, w0.w, w1.x, w1.y, w1.z, w1.w};
      #pragma unroll
      for (int i = 0; i < 8; ++i)
        #pragma unroll
        for (int j = 0; j < 8; ++j) acc[i][j] = fmaf(a[i], w[j], acc[i][j]);
    }
    __syncthreads();
  }

  #pragma unroll
  for (int i = 0; i < 8; ++i) {
    const int r = tr + i;
    if (r < rows) {
      unsigned short* hwp = hw + (size_t)(n0 + r) * 128;
      ushort4 o0, o1;
      o0.x = f2bf(acc[i][0]); o0.y = f2bf(acc[i][1]);
      o0.z = f2bf(acc[i][2]); o0.w = f2bf(acc[i][3]);
      o1.x = f2bf(acc[i][4]); o1.y = f2bf(acc[i][5]);
      o1.z = f2bf(acc[i][6]); o1.w = f2bf(acc[i][7]);
      *(ushort4*)(hwp + tc4) = o0;
      *(ushort4*)(hwp + tc4 + 64) = o1;
    }
  }
}

// ---- GEMM body, bf16 A (layers 2,3: A = hcat slice) -> hw bf16 ------------
__device__ __forceinline__ void gemm128_bf16(
    const unsigned short* __restrict__ A, long long lda,
    const float* __restrict__ W, unsigned short* __restrict__ hw, int N, int n0,
    float (*hsT)[128], float (*Ws)[128]) {
  const int tid = threadIdx.x;
  const int rows = min(128, N - n0);
  const int tc4 = (tid & 15) << 2;
  const int tr = (tid >> 4) << 3;
  float acc[8][8] = {};
  uint4 pa[2];

  auto loadA = [&](int kc) {
    #pragma unroll
    for (int u = 0; u < 2; ++u) {
      const int i = tid + 256 * u;
      const int r = i >> 2, k8 = (i & 3) << 3;
      uint4 v = make_uint4(0u, 0u, 0u, 0u);
      if (r < rows) v = *(const uint4*)(A + (size_t)(n0 + r) * lda + kc + k8);
      pa[u] = v;
    }
  };
  auto stageA = [&]() {
    #pragma unroll
    for (int u = 0; u < 2; ++u) {
      const int i = tid + 256 * u;
      const int r = i >> 2, k8 = (i & 3) << 3;
      float f[8];
      bf8_unpack(pa[u], f);
      #pragma unroll
      for (int t = 0; t < 4; ++t) {
        const int k = k8 + 2 * t;
        const int c = r ^ (k & 28);   // k even -> k,k+1 same 4-group
        hsT[k][c] = f[2 * t];
        hsT[k + 1][c] = f[2 * t + 1];
      }
    }
  };
  auto stageW = [&](int kc) {
    #pragma unroll
    for (int u = 0; u < 4; ++u) {
      const int i = tid + 256 * u;
      const int k = i >> 5, c = (i & 31) << 2;
      *(float4*)&Ws[k][c] = *(const float4*)(W + (size_t)(kc + k) * 128 + c);
    }
  };

  loadA(0);
  for (int kc = 0; kc < 128; kc += 32) {
    stageW(kc);
    stageA();
    __syncthreads();
    if (kc + 32 < 128) loadA(kc + 32);
    #pragma unroll
    for (int k = 0; k < 32; ++k) {
      const int s = k & 28;
      const float4 a0 = *(const float4*)&hsT[k][tr ^ s];
      const float4 a1 = *(const float4*)&hsT[k][(tr + 4) ^ s];
      const float4 w0 = *(const float4*)&Ws[k][tc4];
      const float4 w1 = *(const float4*)&Ws[k][tc4 + 64];
      const float a[8] = {a0.x, a0.y, a0.z, a0.w, a1.x, a1.y, a1.z, a1.w};
      const float w[8] = {w0.x, w0.y, w0.z, w0.w, w1.x, w1.y, w1.z, w1.w};
      #pragma unroll
      for (int i = 0; i < 8; ++i)
        #pragma unroll
        for (int j = 0; j < 8; ++j) acc[i][j] = fmaf(a[i], w[j], acc[i][j]);
    }
    __syncthreads();
  }

  #pragma unroll
  for (int i = 0; i < 8; ++i) {
    const int r = tr + i;
    if (r < rows) {
      unsigned short* hwp = hw + (size_t)(n0 + r) * 128;
      ushort4 o0, o1;
      o0.x = f2bf(acc[i][0]); o0.y = f2bf(acc[i][1]);
      o0.z = f2bf(acc[i][2]); o0.w = f2bf(acc[i][3]);
      o1.x = f2bf(acc[i][4]); o1.y = f2bf(acc[i][5]);
      o1.z = f2bf(acc[i][6]); o1.w = f2bf(acc[i][7]);
      *(ushort4*)(hwp + tc4) = o0;
      *(ushort4*)(hwp + tc4 + 64) = o1;
    }
  }
}

// ---- mega0: [degree count | gemm1 lower 30%] (deg blocks dispatch first) --
__global__ __launch_bounds__(256, 2) void k_mega0(
    const float* __restrict__ x, const float* __restrict__ W1,
    unsigned short* __restrict__ hw, int N, int db,
    const int* __restrict__ coli, int E, int* __restrict__ degi) {
  __shared__ __align__(16) float hsT[32][128];
  __shared__ __align__(16) float Ws[32][128];
  if ((int)blockIdx.x >= db) {
    gemm128_f32(x, 128, W1, hw, N, (blockIdx.x - db) * 128, hsT, Ws);
  } else {
    const int b = blockIdx.x;
    #pragma unroll
    for (int h = 0; h < 2; ++h) {
      const int base = b * 2048 + h * 1024 + (int)threadIdx.x * 4;
      if (base + 3 < E) {
        const int4 c4 = *(const int4*)(coli + base);
        atomicAdd(&degi[c4.x], 1); atomicAdd(&degi[c4.y], 1);
        atomicAdd(&degi[c4.z], 1); atomicAdd(&degi[c4.w], 1);
      } else {
        for (int e = base; e < E; ++e) atomicAdd(&degi[coli[e]], 1);
      }
    }
  }
}

// ---- mega1: [CSR fill | gemm1 upper 70%] (fill blocks dispatch first) -----
__global__ __launch_bounds__(256, 2) void k_mega1(
    const float* __restrict__ x, const float* __restrict__ W1,
    unsigned short* __restrict__ hw, int N, int fb, int goff,
    const int* __restrict__ rowi, const int* __restrict__ coli,
    int* __restrict__ cursor, int* __restrict__ sorted_row, int E) {
  __shared__ __align__(16) float hsT[32][128];
  __shared__ __align__(16) float Ws[32][128];
  if ((int)blockIdx.x >= fb) {
    gemm128_f32(x, 128, W1, hw, N, (goff + blockIdx.x - fb) * 128, hsT, Ws);
  } else {
    const int b = blockIdx.x;
    const int base = b * 1024 + (int)threadIdx.x * 4;
    if (base + 3 < E) {
      const int4 c4 = *(const int4*)(coli + base);
      const int4 r4 = *(const int4*)(rowi + base);
      int p;
      p = atomicAdd(&cursor[c4.x], 1); __builtin_nontemporal_store(r4.x, &sorted_row[p]);
      p = atomicAdd(&cursor[c4.y], 1); __builtin_nontemporal_store(r4.y, &sorted_row[p]);
      p = atomicAdd(&cursor[c4.z], 1); __builtin_nontemporal_store(r4.z, &sorted_row[p]);
      p = atomicAdd(&cursor[c4.w], 1); __builtin_nontemporal_store(r4.w, &sorted_row[p]);
    } else {
      for (int e = base; e < E; ++e) {
        const int p = atomicAdd(&cursor[coli[e]], 1);
        __builtin_nontemporal_store(rowi[e], &sorted_row[p]);
      }
    }
  }
}

// ---- scan pass 1: per-1024-chunk exclusive scan + block sums + dinv -------
__global__ __launch_bounds__(256) void k_scan1(const int* __restrict__ degi, int N,
                                               int* __restrict__ offs,
                                               int* __restrict__ bsums,
                                               float* __restrict__ dinv) {
  __shared__ int sm[256];
  const int b = blockIdx.x, t = threadIdx.x;
  const int base = b * 1024 + t * 4;
  int v[4];
  #pragma unroll
  for (int i = 0; i < 4; ++i) v[i] = (base + i < N) ? degi[base + i] : 0;
  #pragma unroll
  for (int i = 0; i < 4; ++i)
    if (base + i < N) dinv[base + i] = rsqrtf(1.0f + (float)v[i]);
  const int s = v[0] + v[1] + v[2] + v[3];
  sm[t] = s;
  __syncthreads();
  for (int ofs = 1; ofs < 256; ofs <<= 1) {
    const int add = (t >= ofs) ? sm[t - ofs] : 0;
    __syncthreads();
    sm[t] += add;
    __syncthreads();
  }
  if (t == 255) bsums[b] = sm[255];
  int run = sm[t] - s;
  #pragma unroll
  for (int i = 0; i < 4; ++i) {
    if (base + i < N) offs[base + i] = run;
    run += v[i];
  }
}

// ---- scan pass 2: exclusive scan of block sums (nb <= 128) ----------------
__global__ __launch_bounds__(128) void k_scan2(int* __restrict__ bsums, int nb) {
  __shared__ int sm[128];
  const int t = threadIdx.x;
  const int v = (t < nb) ? bsums[t] : 0;
  sm[t] = v;
  __syncthreads();
  for (int ofs = 1; ofs < 128; ofs <<= 1) {
    const int add = (t >= ofs) ? sm[t - ofs] : 0;
    __syncthreads();
    sm[t] += add;
    __syncthreads();
  }
  if (t < nb) bsums[t] = sm[t] - v;
}

// ---- scan pass 3: add block offset; copy to cursor ------------------------
__global__ __launch_bounds__(256) void k_scan3(int* __restrict__ offs,
                                               const int* __restrict__ bsums,
                                               int* __restrict__ cursor, int N) {
  const int add = bsums[blockIdx.x];
  const int base = blockIdx.x * 1024 + threadIdx.x * 4;
  #pragma unroll
  for (int i = 0; i < 4; ++i) {
    const int idx = base + i;
    if (idx < N) {
      const int o = offs[idx] + add;
      offs[idx] = o;
      cursor[idx] = o;
    }
  }
}

// ---- standalone layer GEMM (layers 2,3; bf16 A) ---------------------------
__global__ __launch_bounds__(256, 2) void k_gemm128(
    const unsigned short* __restrict__ A, long long lda,
    const float* __restrict__ W, unsigned short* __restrict__ hw, int N) {
  __shared__ __align__(16) float hsT[32][128];
  __shared__ __align__(16) float Ws[32][128];
  gemm128_bf16(A, lda, W, hw, N, blockIdx.x * 128, hsT, Ws);
}

// ---- segment aggregate (16 lanes/node, ushort8/lane, 8-deep gather) -------
//   hcat[n] = bf16(relu(dinv_n*(dinv_n*hw[n] + sum_in dinv_r*hw[r]) + b))
__global__ __launch_bounds__(256) void k_agg(
    const int* __restrict__ offs, const int* __restrict__ degi,
    const int* __restrict__ sorted_row, const float* __restrict__ dinv,
    const unsigned short* __restrict__ hw, const float* __restrict__ bias,
    unsigned short* __restrict__ hcat, int koff, int N) {
  const int g = (int)((blockIdx.x * 256 + threadIdx.x) >> 4);
  if (g >= N) return;
  const int f8 = (threadIdx.x & 15) << 3;  // 8 features per lane
  const float dc = dinv[g];
  float acc[8];
  {
    const uint4 sv = *(const uint4*)(hw + (size_t)g * 128 + f8);
    float f[8];
    bf8_unpack(sv, f);
    #pragma unroll
    for (int j = 0; j < 8; ++j) acc[j] = dc * f[j];
  }

  const int off = offs[g];
  const int end = off + degi[g];
  int e = off;
  for (; e + 7 < end; e += 8) {  // 8 row-gathers in flight per lane
    int r[8];
    #pragma unroll
    for (int t = 0; t < 8; ++t) r[t] = sorted_row[e + t];
    float dr[8];
    uint4 v[8];
    #pragma unroll
    for (int t = 0; t < 8; ++t) {
      dr[t] = dinv[r[t]];
      v[t] = *(const uint4*)(hw + (size_t)r[t] * 128 + f8);
    }
    #pragma unroll
    for (int t = 0; t < 8; ++t) {
      float f[8];
      bf8_unpack(v[t], f);
      #pragma unroll
      for (int j = 0; j < 8; ++j) acc[j] = fmaf(dr[t], f[j], acc[j]);
    }
  }
  for (; e < end; ++e) {
    const int r0 = sorted_row[e];
    const float d0 = dinv[r0];
    const uint4 v0 = *(const uint4*)(hw + (size_t)r0 * 128 + f8);
    float f[8];
    bf8_unpack(v0, f);
    #pragma unroll
    for (int j = 0; j < 8; ++j) acc[j] = fmaf(d0, f[j], acc[j]);
  }

  const float4 b0 = *(const float4*)(bias + f8);
  const float4 b1 = *(const float4*)(bias + f8 + 4);
  const float bb[8] = {b0.x, b0.y, b0.z, b0.w, b1.x, b1.y, b1.z, b1.w};
  float o[8];
  #pragma unroll
  for (int j = 0; j < 8; ++j) o[j] = fmaxf(fmaf(dc, acc[j], bb[j]), 0.f);
  uint4 st;
  st.x = bfpack(o[0], o[1]); st.y = bfpack(o[2], o[3]);
  st.z = bfpack(o[4], o[5]); st.w = bfpack(o[6], o[7]);
  *(uint4*)(hcat + (size_t)g * 384 + koff + f8) = st;
}

// ---- final: out = hcat(bf16) @ Wlin + blin, K=384, 12 chunks of 32 --------
__global__ __launch_bounds__(256, 2) void k_final(
    const unsigned short* __restrict__ hcat, const float* __restrict__ Wlin,
    const float* __restrict__ blin, float* __restrict__ out, int N) {
  __shared__ __align__(16) float hsT[32][128];  // 16KB
  __shared__ __align__(16) float Ws[32][64];    // 8KB
  const int tid = threadIdx.x;
  const int n0 = blockIdx.x * 128;
  const int rows = min(128, N - n0);
  const int tc = (tid & 15) << 2;
  const int tr = (tid >> 4) << 3;
  float acc[8][4] = {};
  uint4 pa[2];

  auto loadA = [&](int kc) {
    #pragma unroll
    for (int u = 0; u < 2; ++u) {
      const int i = tid + 256 * u;
      const int r = i >> 2, k8 = (i & 3) << 3;
      uint4 v = make_uint4(0u, 0u, 0u, 0u);
      if (r < rows) v = *(const uint4*)(hcat + (size_t)(n0 + r) * 384 + kc + k8);
      pa[u] = v;
    }
  };
  auto stageA = [&]() {
    #pragma unroll
    for (int u = 0; u < 2; ++u) {
      const int i = tid + 256 * u;
      const int r = i >> 2, k8 = (i & 3) << 3;
      float f[8];
      bf8_unpack(pa[u], f);
      #pragma unroll
      for (int t = 0; t < 4; ++t) {
        const int k = k8 + 2 * t;
        const int c = r ^ (k & 28);
        hsT[k][c] = f[2 * t];
        hsT[k + 1][c] = f[2 * t + 1];
      }
    }
  };
  auto stageW = [&](int kc) {
    #pragma unroll
    for (int u = 0; u < 2; ++u) {
      const int i = tid + 256 * u;
      const int k = i >> 4, c = (i & 15) << 2;
      *(float4*)&Ws[k][c] = *(const float4*)(Wlin + (size_t)(kc + k) * 64 + c);
    }
  };

  loadA(0);
  for (int kc = 0; kc < 384; kc += 32) {
    stageW(kc);
    stageA();
    __syncthreads();
    if (kc + 32 < 384) loadA(kc + 32);
    #pragma unroll
    for (int k = 0; k < 32; ++k) {
      const int s = k & 28;
      const float4 a0 = *(const float4*)&hsT[k][tr ^ s];
      const float4 a1 = *(const float4*)&hsT[k][(tr + 4) ^ s];
      const float4 w0 = *(const float4*)&Ws[k][tc];
      const float a[8] = {a0.x, a0.y, a0.z, a0.w, a1.x, a1.y, a1.z, a1.w};
      const float w[4] = {w0.x, w0.y, w0.z, w0.w};
      #pragma unroll
      for (int i = 0; i < 8; ++i)
        #pragma unroll
        for (int j = 0; j < 4; ++j) acc[i][j] = fmaf(a[i], w[j], acc[i][j]);
    }
    __syncthreads();
  }

  #pragma unroll
  for (int i = 0; i < 8; ++i) {
    const int r = tr + i;
    if (r < rows) {
      const float4 bb = *(const float4*)(blin + tc);
      *(float4*)(out + (size_t)(n0 + r) * 64 + tc) =
          make_float4(acc[i][0] + bb.x, acc[i][1] + bb.y,
                      acc[i][2] + bb.z, acc[i][3] + bb.w);
    }
  }
}

extern "C" void kernel_launch(void* const* d_in, const int* in_sizes, int n_in,
                              void* d_out, int out_size, void* d_ws, size_t ws_size,
                              hipStream_t stream) {
  const float* x    = (const float*)d_in[0];
  const int*   ei   = (const int*)d_in[1];
  const float* W1   = (const float*)d_in[2];
  const float* b1   = (const float*)d_in[3];
  const float* W2   = (const float*)d_in[4];
  const float* b2   = (const float*)d_in[5];
  const float* W3   = (const float*)d_in[6];
  const float* b3   = (const float*)d_in[7];
  const float* Wlin = (const float*)d_in[8];
  const float* blin = (const float*)d_in[9];

  const int N = in_sizes[0] / 128;
  const int E = in_sizes[1] / 2;
  const int* rowi = ei;
  const int* coli = ei + E;

  // ws: degi | dinv | offs | cursor | bsums | sorted_row | hw(bf16) | hcat(bf16)
  char* ws = (char*)d_ws;
  const size_t nb4 = (((size_t)N * 4) + 255) & ~(size_t)255;
  int*   degi       = (int*)ws;                 ws += nb4;
  float* dinv       = (float*)ws;               ws += nb4;
  int*   offs       = (int*)ws;                 ws += nb4;
  int*   cursor     = (int*)ws;                 ws += nb4;
  int*   bsums      = (int*)ws;                 ws += 1024;
  int*   sorted_row = (int*)ws;                 ws += (((size_t)E * 4) + 255) & ~(size_t)255;
  unsigned short* hw   = (unsigned short*)ws;   ws += (size_t)N * 128 * 2;
  unsigned short* hcat = (unsigned short*)ws;

  const int nblk = (N + 1023) / 1024;  // <= 128 for N <= 131072
  const int gemmBlocks = (N + 127) / 128;
  const int gb0 = (gemmBlocks * 3) / 10;   // gemm1 share in mega0 (covers deg)
  const int gb1 = gemmBlocks - gb0;        // gemm1 share in mega1 (covers fill)
  const int degBlocks  = (E + 2047) / 2048;
  const int fillBlocks = (E + 1023) / 1024;
  const int aggBlocks  = (N + 15) / 16;

  hipMemsetAsync(degi, 0, (size_t)N * 4, stream);
  k_mega0<<<degBlocks + gb0, 256, 0, stream>>>(x, W1, hw, N, degBlocks,
                                               coli, E, degi);
  k_scan1<<<nblk, 256, 0, stream>>>(degi, N, offs, bsums, dinv);
  k_scan2<<<1, 128, 0, stream>>>(bsums, nblk);
  k_scan3<<<nblk, 256, 0, stream>>>(offs, bsums, cursor, N);
  k_mega1<<<fillBlocks + gb1, 256, 0, stream>>>(x, W1, hw, N, fillBlocks, gb0,
                                                rowi, coli, cursor, sorted_row, E);

  k_agg<<<aggBlocks, 256, 0, stream>>>(offs, degi, sorted_row, dinv, hw,
                                       b1, hcat, 0, N);
  k_gemm128<<<gemmBlocks, 256, 0, stream>>>(hcat, 384, W2, hw, N);
  k_agg<<<aggBlocks, 256, 0, stream>>>(offs, degi, sorted_row, dinv, hw,
                                       b2, hcat, 128, N);
  k_gemm128<<<gemmBlocks, 256, 0, stream>>>(hcat + 128, 384, W3, hw, N);
  k_agg<<<aggBlocks, 256, 0, stream>>>(offs, degi, sorted_row, dinv, hw,
                                       b3, hcat, 256, N);
  k_final<<<gemmBlocks, 256, 0, stream>>>(hcat, Wlin, blin, (float*)d_out, N);
}

// Round 10
// 583.364 us; speedup vs baseline: 1.0803x; 1.0803x over previous
//
#include <hip/hip_runtime.h>
#include <hip/hip_bf16.h>

// ---------------------------------------------------------------------------
// GCN via device-built CSR (no f32 atomics), all inter-kernel tensors bf16:
//   mega0 = [gemm1 50% | deg count]   mega1 = [gemm1 50% | CSR fill]
//   (gemm blocks FIRST in grid: in-order dispatch seats VALU-heavy gemm
//    blocks on CUs, latency-bound scatter blocks trickle in behind ->
//    per-CU overlap. Scatter-first serializes the phases: r9 +100us.)
//   3x [ hw = bf16(hprev @ W) ;
//        hcat_k[n] = bf16(relu(dinv_n*(dinv_n*hw[n] + sum_in dinv_r*hw[r])+b)) ]
//   out = hcat @ Wlin + blin   (f32 out)
// k_agg: 16 lanes/node x ushort8 -> 4 nodes/wave, 8-deep gather unroll.
// GEMMs: K=32 LDS chunks, A-stream reg prefetch, W direct to LDS,
// __launch_bounds__(256,2) = 128-VGPR cap = spill-free (arg>=3 spills).
// ---------------------------------------------------------------------------

__device__ __forceinline__ unsigned short f2bf(float f) {  // RNE f32->bf16
  unsigned int u = __float_as_uint(f);
  u += 0x7FFFu + ((u >> 16) & 1u);
  return (unsigned short)(u >> 16);
}
__device__ __forceinline__ float bf2f(unsigned short h) {
  return __uint_as_float((unsigned int)h << 16);
}
__device__ __forceinline__ unsigned int bfpack(float a, float b) {
  return ((unsigned int)f2bf(a)) | ((unsigned int)f2bf(b) << 16);
}
__device__ __forceinline__ void bf8_unpack(uint4 v, float* f) {
  f[0] = __uint_as_float(v.x << 16); f[1] = __uint_as_float(v.x & 0xFFFF0000u);
  f[2] = __uint_as_float(v.y << 16); f[3] = __uint_as_float(v.y & 0xFFFF0000u);
  f[4] = __uint_as_float(v.z << 16); f[5] = __uint_as_float(v.z & 0xFFFF0000u);
  f[6] = __uint_as_float(v.w << 16); f[7] = __uint_as_float(v.w & 0xFFFF0000u);
}

// ---- GEMM body, f32 A (layer 1: A = x) -> hw bf16 -------------------------
__device__ __forceinline__ void gemm128_f32(
    const float* __restrict__ A, long long lda,
    const float* __restrict__ W, unsigned short* __restrict__ hw, int N, int n0,
    float (*hsT)[128], float (*Ws)[128]) {
  const int tid = threadIdx.x;
  const int rows = min(128, N - n0);
  const int tc4 = (tid & 15) << 2;   // col group 1: tc4..+3; group 2: +64
  const int tr = (tid >> 4) << 3;
  float acc[8][8] = {};
  float4 pa[4];

  auto loadA = [&](int kc) {
    #pragma unroll
    for (int u = 0; u < 4; ++u) {
      const int i = tid + 256 * u;
      const int r = i >> 3, k4 = (i & 7) << 2;
      float4 v = make_float4(0.f, 0.f, 0.f, 0.f);
      if (r < rows) v = *(const float4*)(A + (size_t)(n0 + r) * lda + kc + k4);
      pa[u] = v;
    }
  };
  auto stageA = [&]() {
    #pragma unroll
    for (int u = 0; u < 4; ++u) {
      const int i = tid + 256 * u;
      const int r = i >> 3, k4 = (i & 7) << 2;
      const int c = r ^ k4;
      hsT[k4 + 0][c] = pa[u].x; hsT[k4 + 1][c] = pa[u].y;
      hsT[k4 + 2][c] = pa[u].z; hsT[k4 + 3][c] = pa[u].w;
    }
  };
  auto stageW = [&](int kc) {
    #pragma unroll
    for (int u = 0; u < 4; ++u) {
      const int i = tid + 256 * u;
      const int k = i >> 5, c = (i & 31) << 2;
      *(float4*)&Ws[k][c] = *(const float4*)(W + (size_t)(kc + k) * 128 + c);
    }
  };

  loadA(0);
  for (int kc = 0; kc < 128; kc += 32) {
    stageW(kc);
    stageA();
    __syncthreads();
    if (kc + 32 < 128) loadA(kc + 32);
    #pragma unroll
    for (int k = 0; k < 32; ++k) {
      const int s = k & 28;
      const float4 a0 = *(const float4*)&hsT[k][tr ^ s];
      const float4 a1 = *(const float4*)&hsT[k][(tr + 4) ^ s];
      const float4 w0 = *(const float4*)&Ws[k][tc4];
      const float4 w1 = *(const float4*)&Ws[k][tc4 + 64];
      const float a[8] = {a0.x, a0.y, a0.z, a0.w, a1.x, a1.y, a1.z, a1.w};
      const float w[8] = {w0.x, w0.y, w0.z, w0.w, w1.x, w1.y, w1.z, w1.w};
      #pragma unroll
      for (int i = 0; i < 8; ++i)
        #pragma unroll
        for (int j = 0; j < 8; ++j) acc[i][j] = fmaf(a[i], w[j], acc[i][j]);
    }
    __syncthreads();
  }

  #pragma unroll
  for (int i = 0; i < 8; ++i) {
    const int r = tr + i;
    if (r < rows) {
      unsigned short* hwp = hw + (size_t)(n0 + r) * 128;
      ushort4 o0, o1;
      o0.x = f2bf(acc[i][0]); o0.y = f2bf(acc[i][1]);
      o0.z = f2bf(acc[i][2]); o0.w = f2bf(acc[i][3]);
      o1.x = f2bf(acc[i][4]); o1.y = f2bf(acc[i][5]);
      o1.z = f2bf(acc[i][6]); o1.w = f2bf(acc[i][7]);
      *(ushort4*)(hwp + tc4) = o0;
      *(ushort4*)(hwp + tc4 + 64) = o1;
    }
  }
}

// ---- GEMM body, bf16 A (layers 2,3: A = hcat slice) -> hw bf16 ------------
__device__ __forceinline__ void gemm128_bf16(
    const unsigned short* __restrict__ A, long long lda,
    const float* __restrict__ W, unsigned short* __restrict__ hw, int N, int n0,
    float (*hsT)[128], float (*Ws)[128]) {
  const int tid = threadIdx.x;
  const int rows = min(128, N - n0);
  const int tc4 = (tid & 15) << 2;
  const int tr = (tid >> 4) << 3;
  float acc[8][8] = {};
  uint4 pa[2];

  auto loadA = [&](int kc) {
    #pragma unroll
    for (int u = 0; u < 2; ++u) {
      const int i = tid + 256 * u;
      const int r = i >> 2, k8 = (i & 3) << 3;
      uint4 v = make_uint4(0u, 0u, 0u, 0u);
      if (r < rows) v = *(const uint4*)(A + (size_t)(n0 + r) * lda + kc + k8);
      pa[u] = v;
    }
  };
  auto stageA = [&]() {
    #pragma unroll
    for (int u = 0; u < 2; ++u) {
      const int i = tid + 256 * u;
      const int r = i >> 2, k8 = (i & 3) << 3;
      float f[8];
      bf8_unpack(pa[u], f);
      #pragma unroll
      for (int t = 0; t < 4; ++t) {
        const int k = k8 + 2 * t;
        const int c = r ^ (k & 28);   // k even -> k,k+1 same 4-group
        hsT[k][c] = f[2 * t];
        hsT[k + 1][c] = f[2 * t + 1];
      }
    }
  };
  auto stageW = [&](int kc) {
    #pragma unroll
    for (int u = 0; u < 4; ++u) {
      const int i = tid + 256 * u;
      const int k = i >> 5, c = (i & 31) << 2;
      *(float4*)&Ws[k][c] = *(const float4*)(W + (size_t)(kc + k) * 128 + c);
    }
  };

  loadA(0);
  for (int kc = 0; kc < 128; kc += 32) {
    stageW(kc);
    stageA();
    __syncthreads();
    if (kc + 32 < 128) loadA(kc + 32);
    #pragma unroll
    for (int k = 0; k < 32; ++k) {
      const int s = k & 28;
      const float4 a0 = *(const float4*)&hsT[k][tr ^ s];
      const float4 a1 = *(const float4*)&hsT[k][(tr + 4) ^ s];
      const float4 w0 = *(const float4*)&Ws[k][tc4];
      const float4 w1 = *(const float4*)&Ws[k][tc4 + 64];
      const float a[8] = {a0.x, a0.y, a0.z, a0.w, a1.x, a1.y, a1.z, a1.w};
      const float w[8] = {w0.x, w0.y, w0.z, w0.w, w1.x, w1.y, w1.z, w1.w};
      #pragma unroll
      for (int i = 0; i < 8; ++i)
        #pragma unroll
        for (int j = 0; j < 8; ++j) acc[i][j] = fmaf(a[i], w[j], acc[i][j]);
    }
    __syncthreads();
  }

  #pragma unroll
  for (int i = 0; i < 8; ++i) {
    const int r = tr + i;
    if (r < rows) {
      unsigned short* hwp = hw + (size_t)(n0 + r) * 128;
      ushort4 o0, o1;
      o0.x = f2bf(acc[i][0]); o0.y = f2bf(acc[i][1]);
      o0.z = f2bf(acc[i][2]); o0.w = f2bf(acc[i][3]);
      o1.x = f2bf(acc[i][4]); o1.y = f2bf(acc[i][5]);
      o1.z = f2bf(acc[i][6]); o1.w = f2bf(acc[i][7]);
      *(ushort4*)(hwp + tc4) = o0;
      *(ushort4*)(hwp + tc4 + 64) = o1;
    }
  }
}

// ---- mega0: [gemm1 lower half | degree count] (gemm blocks first) ---------
__global__ __launch_bounds__(256, 2) void k_mega0(
    const float* __restrict__ x, const float* __restrict__ W1,
    unsigned short* __restrict__ hw, int N, int gb,
    const int* __restrict__ coli, int E, int* __restrict__ degi) {
  __shared__ __align__(16) float hsT[32][128];
  __shared__ __align__(16) float Ws[32][128];
  if ((int)blockIdx.x < gb) {
    gemm128_f32(x, 128, W1, hw, N, blockIdx.x * 128, hsT, Ws);
  } else {
    const int b = blockIdx.x - gb;
    #pragma unroll
    for (int h = 0; h < 2; ++h) {
      const int base = b * 2048 + h * 1024 + (int)threadIdx.x * 4;
      if (base + 3 < E) {
        const int4 c4 = *(const int4*)(coli + base);
        atomicAdd(&degi[c4.x], 1); atomicAdd(&degi[c4.y], 1);
        atomicAdd(&degi[c4.z], 1); atomicAdd(&degi[c4.w], 1);
      } else {
        for (int e = base; e < E; ++e) atomicAdd(&degi[coli[e]], 1);
      }
    }
  }
}

// ---- mega1: [gemm1 upper half | CSR fill] (gemm blocks first) -------------
__global__ __launch_bounds__(256, 2) void k_mega1(
    const float* __restrict__ x, const float* __restrict__ W1,
    unsigned short* __restrict__ hw, int N, int gb, int goff,
    const int* __restrict__ rowi, const int* __restrict__ coli,
    int* __restrict__ cursor, int* __restrict__ sorted_row, int E) {
  __shared__ __align__(16) float hsT[32][128];
  __shared__ __align__(16) float Ws[32][128];
  if ((int)blockIdx.x < gb) {
    gemm128_f32(x, 128, W1, hw, N, (goff + blockIdx.x) * 128, hsT, Ws);
  } else {
    const int b = blockIdx.x - gb;
    const int base = b * 1024 + (int)threadIdx.x * 4;
    if (base + 3 < E) {
      const int4 c4 = *(const int4*)(coli + base);
      const int4 r4 = *(const int4*)(rowi + base);
      int p;
      p = atomicAdd(&cursor[c4.x], 1); __builtin_nontemporal_store(r4.x, &sorted_row[p]);
      p = atomicAdd(&cursor[c4.y], 1); __builtin_nontemporal_store(r4.y, &sorted_row[p]);
      p = atomicAdd(&cursor[c4.z], 1); __builtin_nontemporal_store(r4.z, &sorted_row[p]);
      p = atomicAdd(&cursor[c4.w], 1); __builtin_nontemporal_store(r4.w, &sorted_row[p]);
    } else {
      for (int e = base; e < E; ++e) {
        const int p = atomicAdd(&cursor[coli[e]], 1);
        __builtin_nontemporal_store(rowi[e], &sorted_row[p]);
      }
    }
  }
}

// ---- scan pass 1: per-1024-chunk exclusive scan + block sums + dinv -------
__global__ __launch_bounds__(256) void k_scan1(const int* __restrict__ degi, int N,
                                               int* __restrict__ offs,
                                               int* __restrict__ bsums,
                                               float* __restrict__ dinv) {
  __shared__ int sm[256];
  const int b = blockIdx.x, t = threadIdx.x;
  const int base = b * 1024 + t * 4;
  int v[4];
  #pragma unroll
  for (int i = 0; i < 4; ++i) v[i] = (base + i < N) ? degi[base + i] : 0;
  #pragma unroll
  for (int i = 0; i < 4; ++i)
    if (base + i < N) dinv[base + i] = rsqrtf(1.0f + (float)v[i]);
  const int s = v[0] + v[1] + v[2] + v[3];
  sm[t] = s;
  __syncthreads();
  for (int ofs = 1; ofs < 256; ofs <<= 1) {
    const int add = (t >= ofs) ? sm[t - ofs] : 0;
    __syncthreads();
    sm[t] += add;
    __syncthreads();
  }
  if (t == 255) bsums[b] = sm[255];
  int run = sm[t] - s;
  #pragma unroll
  for (int i = 0; i < 4; ++i) {
    if (base + i < N) offs[base + i] = run;
    run += v[i];
  }
}

// ---- scan pass 2: exclusive scan of block sums (nb <= 128) ----------------
__global__ __launch_bounds__(128) void k_scan2(int* __restrict__ bsums, int nb) {
  __shared__ int sm[128];
  const int t = threadIdx.x;
  const int v = (t < nb) ? bsums[t] : 0;
  sm[t] = v;
  __syncthreads();
  for (int ofs = 1; ofs < 128; ofs <<= 1) {
    const int add = (t >= ofs) ? sm[t - ofs] : 0;
    __syncthreads();
    sm[t] += add;
    __syncthreads();
  }
  if (t < nb) bsums[t] = sm[t] - v;
}

// ---- scan pass 3: add block offset; copy to cursor ------------------------
__global__ __launch_bounds__(256) void k_scan3(int* __restrict__ offs,
                                               const int* __restrict__ bsums,
                                               int* __restrict__ cursor, int N) {
  const int add = bsums[blockIdx.x];
  const int base = blockIdx.x * 1024 + threadIdx.x * 4;
  #pragma unroll
  for (int i = 0; i < 4; ++i) {
    const int idx = base + i;
    if (idx < N) {
      const int o = offs[idx] + add;
      offs[idx] = o;
      cursor[idx] = o;
    }
  }
}

// ---- standalone layer GEMM (layers 2,3; bf16 A) ---------------------------
__global__ __launch_bounds__(256, 2) void k_gemm128(
    const unsigned short* __restrict__ A, long long lda,
    const float* __restrict__ W, unsigned short* __restrict__ hw, int N) {
  __shared__ __align__(16) float hsT[32][128];
  __shared__ __align__(16) float Ws[32][128];
  gemm128_bf16(A, lda, W, hw, N, blockIdx.x * 128, hsT, Ws);
}

// ---- segment aggregate (16 lanes/node, ushort8/lane, 8-deep gather) -------
//   hcat[n] = bf16(relu(dinv_n*(dinv_n*hw[n] + sum_in dinv_r*hw[r]) + b))
__global__ __launch_bounds__(256) void k_agg(
    const int* __restrict__ offs, const int* __restrict__ degi,
    const int* __restrict__ sorted_row, const float* __restrict__ dinv,
    const unsigned short* __restrict__ hw, const float* __restrict__ bias,
    unsigned short* __restrict__ hcat, int koff, int N) {
  const int g = (int)((blockIdx.x * 256 + threadIdx.x) >> 4);
  if (g >= N) return;
  const int f8 = (threadIdx.x & 15) << 3;  // 8 features per lane
  const float dc = dinv[g];
  float acc[8];
  {
    const uint4 sv = *(const uint4*)(hw + (size_t)g * 128 + f8);
    float f[8];
    bf8_unpack(sv, f);
    #pragma unroll
    for (int j = 0; j < 8; ++j) acc[j] = dc * f[j];
  }

  const int off = offs[g];
  const int end = off + degi[g];
  int e = off;
  for (; e + 7 < end; e += 8) {  // 8 row-gathers in flight per lane
    int r[8];
    #pragma unroll
    for (int t = 0; t < 8; ++t) r[t] = sorted_row[e + t];
    float dr[8];
    uint4 v[8];
    #pragma unroll
    for (int t = 0; t < 8; ++t) {
      dr[t] = dinv[r[t]];
      v[t] = *(const uint4*)(hw + (size_t)r[t] * 128 + f8);
    }
    #pragma unroll
    for (int t = 0; t < 8; ++t) {
      float f[8];
      bf8_unpack(v[t], f);
      #pragma unroll
      for (int j = 0; j < 8; ++j) acc[j] = fmaf(dr[t], f[j], acc[j]);
    }
  }
  for (; e < end; ++e) {
    const int r0 = sorted_row[e];
    const float d0 = dinv[r0];
    const uint4 v0 = *(const uint4*)(hw + (size_t)r0 * 128 + f8);
    float f[8];
    bf8_unpack(v0, f);
    #pragma unroll
    for (int j = 0; j < 8; ++j) acc[j] = fmaf(d0, f[j], acc[j]);
  }

  const float4 b0 = *(const float4*)(bias + f8);
  const float4 b1 = *(const float4*)(bias + f8 + 4);
  const float bb[8] = {b0.x, b0.y, b0.z, b0.w, b1.x, b1.y, b1.z, b1.w};
  float o[8];
  #pragma unroll
  for (int j = 0; j < 8; ++j) o[j] = fmaxf(fmaf(dc, acc[j], bb[j]), 0.f);
  uint4 st;
  st.x = bfpack(o[0], o[1]); st.y = bfpack(o[2], o[3]);
  st.z = bfpack(o[4], o[5]); st.w = bfpack(o[6], o[7]);
  *(uint4*)(hcat + (size_t)g * 384 + koff + f8) = st;
}

// ---- final: out = hcat(bf16) @ Wlin + blin, K=384, 12 chunks of 32 --------
__global__ __launch_bounds__(256, 2) void k_final(
    const unsigned short* __restrict__ hcat, const float* __restrict__ Wlin,
    const float* __restrict__ blin, float* __restrict__ out, int N) {
  __shared__ __align__(16) float hsT[32][128];  // 16KB
  __shared__ __align__(16) float Ws[32][64];    // 8KB
  const int tid = threadIdx.x;
  const int n0 = blockIdx.x * 128;
  const int rows = min(128, N - n0);
  const int tc = (tid & 15) << 2;
  const int tr = (tid >> 4) << 3;
  float acc[8][4] = {};
  uint4 pa[2];

  auto loadA = [&](int kc) {
    #pragma unroll
    for (int u = 0; u < 2; ++u) {
      const int i = tid + 256 * u;
      const int r = i >> 2, k8 = (i & 3) << 3;
      uint4 v = make_uint4(0u, 0u, 0u, 0u);
      if (r < rows) v = *(const uint4*)(hcat + (size_t)(n0 + r) * 384 + kc + k8);
      pa[u] = v;
    }
  };
  auto stageA = [&]() {
    #pragma unroll
    for (int u = 0; u < 2; ++u) {
      const int i = tid + 256 * u;
      const int r = i >> 2, k8 = (i & 3) << 3;
      float f[8];
      bf8_unpack(pa[u], f);
      #pragma unroll
      for (int t = 0; t < 4; ++t) {
        const int k = k8 + 2 * t;
        const int c = r ^ (k & 28);
        hsT[k][c] = f[2 * t];
        hsT[k + 1][c] = f[2 * t + 1];
      }
    }
  };
  auto stageW = [&](int kc) {
    #pragma unroll
    for (int u = 0; u < 2; ++u) {
      const int i = tid + 256 * u;
      const int k = i >> 4, c = (i & 15) << 2;
      *(float4*)&Ws[k][c] = *(const float4*)(Wlin + (size_t)(kc + k) * 64 + c);
    }
  };

  loadA(0);
  for (int kc = 0; kc < 384; kc += 32) {
    stageW(kc);
    stageA();
    __syncthreads();
    if (kc + 32 < 384) loadA(kc + 32);
    #pragma unroll
    for (int k = 0; k < 32; ++k) {
      const int s = k & 28;
      const float4 a0 = *(const float4*)&hsT[k][tr ^ s];
      const float4 a1 = *(const float4*)&hsT[k][(tr + 4) ^ s];
      const float4 w0 = *(const float4*)&Ws[k][tc];
      const float a[8] = {a0.x, a0.y, a0.z, a0.w, a1.x, a1.y, a1.z, a1.w};
      const float w[4] = {w0.x, w0.y, w0.z, w0.w};
      #pragma unroll
      for (int i = 0; i < 8; ++i)
        #pragma unroll
        for (int j = 0; j < 4; ++j) acc[i][j] = fmaf(a[i], w[j], acc[i][j]);
    }
    __syncthreads();
  }

  #pragma unroll
  for (int i = 0; i < 8; ++i) {
    const int r = tr + i;
    if (r < rows) {
      const float4 bb = *(const float4*)(blin + tc);
      *(float4*)(out + (size_t)(n0 + r) * 64 + tc) =
          make_float4(acc[i][0] + bb.x, acc[i][1] + bb.y,
                      acc[i][2] + bb.z, acc[i][3] + bb.w);
    }
  }
}

extern "C" void kernel_launch(void* const* d_in, const int* in_sizes, int n_in,
                              void* d_out, int out_size, void* d_ws, size_t ws_size,
                              hipStream_t stream) {
  const float* x    = (const float*)d_in[0];
  const int*   ei   = (const int*)d_in[1];
  const float* W1   = (const float*)d_in[2];
  const float* b1   = (const float*)d_in[3];
  const float* W2   = (const float*)d_in[4];
  const float* b2   = (const float*)d_in[5];
  const float* W3   = (const float*)d_in[6];
  const float* b3   = (const float*)d_in[7];
  const float* Wlin = (const float*)d_in[8];
  const float* blin = (const float*)d_in[9];

  const int N = in_sizes[0] / 128;
  const int E = in_sizes[1] / 2;
  const int* rowi = ei;
  const int* coli = ei + E;

  // ws: degi | dinv | offs | cursor | bsums | sorted_row | hw(bf16) | hcat(bf16)
  char* ws = (char*)d_ws;
  const size_t nb4 = (((size_t)N * 4) + 255) & ~(size_t)255;
  int*   degi       = (int*)ws;                 ws += nb4;
  float* dinv       = (float*)ws;               ws += nb4;
  int*   offs       = (int*)ws;                 ws += nb4;
  int*   cursor     = (int*)ws;                 ws += nb4;
  int*   bsums      = (int*)ws;                 ws += 1024;
  int*   sorted_row = (int*)ws;                 ws += (((size_t)E * 4) + 255) & ~(size_t)255;
  unsigned short* hw   = (unsigned short*)ws;   ws += (size_t)N * 128 * 2;
  unsigned short* hcat = (unsigned short*)ws;

  const int nblk = (N + 1023) / 1024;  // <= 128 for N <= 131072
  const int gemmBlocks = (N + 127) / 128;
  const int gb0 = gemmBlocks / 2;          // gemm1 lower half (mega0)
  const int gb1 = gemmBlocks - gb0;        // gemm1 upper half (mega1)
  const int degBlocks  = (E + 2047) / 2048;
  const int fillBlocks = (E + 1023) / 1024;
  const int aggBlocks  = (N + 15) / 16;

  hipMemsetAsync(degi, 0, (size_t)N * 4, stream);
  k_mega0<<<gb0 + degBlocks, 256, 0, stream>>>(x, W1, hw, N, gb0, coli, E, degi);
  k_scan1<<<nblk, 256, 0, stream>>>(degi, N, offs, bsums, dinv);
  k_scan2<<<1, 128, 0, stream>>>(bsums, nblk);
  k_scan3<<<nblk, 256, 0, stream>>>(offs, bsums, cursor, N);
  k_mega1<<<gb1 + fillBlocks, 256, 0, stream>>>(x, W1, hw, N, gb1, gb0,
                                                rowi, coli, cursor, sorted_row, E);

  k_agg<<<aggBlocks, 256, 0, stream>>>(offs, degi, sorted_row, dinv, hw,
                                       b1, hcat, 0, N);
  k_gemm128<<<gemmBlocks, 256, 0, stream>>>(hcat, 384, W2, hw, N);
  k_agg<<<aggBlocks, 256, 0, stream>>>(offs, degi, sorted_row, dinv, hw,
                                       b2, hcat, 128, N);
  k_gemm128<<<gemmBlocks, 256, 0, stream>>>(hcat + 128, 384, W3, hw, N);
  k_agg<<<aggBlocks, 256, 0, stream>>>(offs, degi, sorted_row, dinv, hw,
                                       b3, hcat, 256, N);
  k_final<<<gemmBlocks, 256, 0, stream>>>(hcat, Wlin, blin, (float*)d_out, N);
}

// Round 11
// 557.639 us; speedup vs baseline: 1.1301x; 1.0461x over previous
//
#include <hip/hip_runtime.h>
#include <hip/hip_bf16.h>

// ---------------------------------------------------------------------------
// GCN via device-built CSR (no f32 atomics), all inter-kernel tensors bf16:
//   mega0 = [gemm1 50% | deg count]   mega1 = [gemm1 50% | CSR fill]
//   (gemm blocks FIRST in grid: in-order dispatch seats VALU-heavy gemm
//    blocks on CUs, latency-bound scatter blocks trickle in behind.)
//   3x [ hw = bf16(hprev @ W) ;
//        hcat_k[n] = bf16(relu(dinv_n*(dinv_n*hw[n] + sum_in dinv_r*hw[r])+b)) ]
//   out = hcat @ Wlin + blin   (f32 out)
// k_agg: 32 lanes/node (2 nodes/wave -> min degree-divergence), ushort4
// gather (256B/edge coalesced), packed-bf16 uint2 hcat store, 8-deep unroll.
// GEMMs: K=32 LDS chunks, A-stream reg prefetch, W direct to LDS,
// __launch_bounds__(256,2) = 128-VGPR cap = spill-free (arg>=3 spills).
// ---------------------------------------------------------------------------

__device__ __forceinline__ unsigned short f2bf(float f) {  // RNE f32->bf16
  unsigned int u = __float_as_uint(f);
  u += 0x7FFFu + ((u >> 16) & 1u);
  return (unsigned short)(u >> 16);
}
__device__ __forceinline__ float bf2f(unsigned short h) {
  return __uint_as_float((unsigned int)h << 16);
}
__device__ __forceinline__ unsigned int bfpack(float a, float b) {
  return ((unsigned int)f2bf(a)) | ((unsigned int)f2bf(b) << 16);
}
__device__ __forceinline__ void bf4_unpack(uint2 v, float* f) {
  f[0] = __uint_as_float(v.x << 16); f[1] = __uint_as_float(v.x & 0xFFFF0000u);
  f[2] = __uint_as_float(v.y << 16); f[3] = __uint_as_float(v.y & 0xFFFF0000u);
}
__device__ __forceinline__ void bf8_unpack(uint4 v, float* f) {
  f[0] = __uint_as_float(v.x << 16); f[1] = __uint_as_float(v.x & 0xFFFF0000u);
  f[2] = __uint_as_float(v.y << 16); f[3] = __uint_as_float(v.y & 0xFFFF0000u);
  f[4] = __uint_as_float(v.z << 16); f[5] = __uint_as_float(v.z & 0xFFFF0000u);
  f[6] = __uint_as_float(v.w << 16); f[7] = __uint_as_float(v.w & 0xFFFF0000u);
}

// ---- GEMM body, f32 A (layer 1: A = x) -> hw bf16 -------------------------
__device__ __forceinline__ void gemm128_f32(
    const float* __restrict__ A, long long lda,
    const float* __restrict__ W, unsigned short* __restrict__ hw, int N, int n0,
    float (*hsT)[128], float (*Ws)[128]) {
  const int tid = threadIdx.x;
  const int rows = min(128, N - n0);
  const int tc4 = (tid & 15) << 2;   // col group 1: tc4..+3; group 2: +64
  const int tr = (tid >> 4) << 3;
  float acc[8][8] = {};
  float4 pa[4];

  auto loadA = [&](int kc) {
    #pragma unroll
    for (int u = 0; u < 4; ++u) {
      const int i = tid + 256 * u;
      const int r = i >> 3, k4 = (i & 7) << 2;
      float4 v = make_float4(0.f, 0.f, 0.f, 0.f);
      if (r < rows) v = *(const float4*)(A + (size_t)(n0 + r) * lda + kc + k4);
      pa[u] = v;
    }
  };
  auto stageA = [&]() {
    #pragma unroll
    for (int u = 0; u < 4; ++u) {
      const int i = tid + 256 * u;
      const int r = i >> 3, k4 = (i & 7) << 2;
      const int c = r ^ k4;
      hsT[k4 + 0][c] = pa[u].x; hsT[k4 + 1][c] = pa[u].y;
      hsT[k4 + 2][c] = pa[u].z; hsT[k4 + 3][c] = pa[u].w;
    }
  };
  auto stageW = [&](int kc) {
    #pragma unroll
    for (int u = 0; u < 4; ++u) {
      const int i = tid + 256 * u;
      const int k = i >> 5, c = (i & 31) << 2;
      *(float4*)&Ws[k][c] = *(const float4*)(W + (size_t)(kc + k) * 128 + c);
    }
  };

  loadA(0);
  for (int kc = 0; kc < 128; kc += 32) {
    stageW(kc);
    stageA();
    __syncthreads();
    if (kc + 32 < 128) loadA(kc + 32);
    #pragma unroll
    for (int k = 0; k < 32; ++k) {
      const int s = k & 28;
      const float4 a0 = *(const float4*)&hsT[k][tr ^ s];
      const float4 a1 = *(const float4*)&hsT[k][(tr + 4) ^ s];
      const float4 w0 = *(const float4*)&Ws[k][tc4];
      const float4 w1 = *(const float4*)&Ws[k][tc4 + 64];
      const float a[8] = {a0.x, a0.y, a0.z, a0.w, a1.x, a1.y, a1.z, a1.w};
      const float w[8] = {w0.x, w0.y, w0.z, w0.w, w1.x, w1.y, w1.z, w1.w};
      #pragma unroll
      for (int i = 0; i < 8; ++i)
        #pragma unroll
        for (int j = 0; j < 8; ++j) acc[i][j] = fmaf(a[i], w[j], acc[i][j]);
    }
    __syncthreads();
  }

  #pragma unroll
  for (int i = 0; i < 8; ++i) {
    const int r = tr + i;
    if (r < rows) {
      unsigned short* hwp = hw + (size_t)(n0 + r) * 128;
      ushort4 o0, o1;
      o0.x = f2bf(acc[i][0]); o0.y = f2bf(acc[i][1]);
      o0.z = f2bf(acc[i][2]); o0.w = f2bf(acc[i][3]);
      o1.x = f2bf(acc[i][4]); o1.y = f2bf(acc[i][5]);
      o1.z = f2bf(acc[i][6]); o1.w = f2bf(acc[i][7]);
      *(ushort4*)(hwp + tc4) = o0;
      *(ushort4*)(hwp + tc4 + 64) = o1;
    }
  }
}

// ---- GEMM body, bf16 A (layers 2,3: A = hcat slice) -> hw bf16 ------------
__device__ __forceinline__ void gemm128_bf16(
    const unsigned short* __restrict__ A, long long lda,
    const float* __restrict__ W, unsigned short* __restrict__ hw, int N, int n0,
    float (*hsT)[128], float (*Ws)[128]) {
  const int tid = threadIdx.x;
  const int rows = min(128, N - n0);
  const int tc4 = (tid & 15) << 2;
  const int tr = (tid >> 4) << 3;
  float acc[8][8] = {};
  uint4 pa[2];

  auto loadA = [&](int kc) {
    #pragma unroll
    for (int u = 0; u < 2; ++u) {
      const int i = tid + 256 * u;
      const int r = i >> 2, k8 = (i & 3) << 3;
      uint4 v = make_uint4(0u, 0u, 0u, 0u);
      if (r < rows) v = *(const uint4*)(A + (size_t)(n0 + r) * lda + kc + k8);
      pa[u] = v;
    }
  };
  auto stageA = [&]() {
    #pragma unroll
    for (int u = 0; u < 2; ++u) {
      const int i = tid + 256 * u;
      const int r = i >> 2, k8 = (i & 3) << 3;
      float f[8];
      bf8_unpack(pa[u], f);
      #pragma unroll
      for (int t = 0; t < 4; ++t) {
        const int k = k8 + 2 * t;
        const int c = r ^ (k & 28);   // k even -> k,k+1 same 4-group
        hsT[k][c] = f[2 * t];
        hsT[k + 1][c] = f[2 * t + 1];
      }
    }
  };
  auto stageW = [&](int kc) {
    #pragma unroll
    for (int u = 0; u < 4; ++u) {
      const int i = tid + 256 * u;
      const int k = i >> 5, c = (i & 31) << 2;
      *(float4*)&Ws[k][c] = *(const float4*)(W + (size_t)(kc + k) * 128 + c);
    }
  };

  loadA(0);
  for (int kc = 0; kc < 128; kc += 32) {
    stageW(kc);
    stageA();
    __syncthreads();
    if (kc + 32 < 128) loadA(kc + 32);
    #pragma unroll
    for (int k = 0; k < 32; ++k) {
      const int s = k & 28;
      const float4 a0 = *(const float4*)&hsT[k][tr ^ s];
      const float4 a1 = *(const float4*)&hsT[k][(tr + 4) ^ s];
      const float4 w0 = *(const float4*)&Ws[k][tc4];
      const float4 w1 = *(const float4*)&Ws[k][tc4 + 64];
      const float a[8] = {a0.x, a0.y, a0.z, a0.w, a1.x, a1.y, a1.z, a1.w};
      const float w[8] = {w0.x, w0.y, w0.z, w0.w, w1.x, w1.y, w1.z, w1.w};
      #pragma unroll
      for (int i = 0; i < 8; ++i)
        #pragma unroll
        for (int j = 0; j < 8; ++j) acc[i][j] = fmaf(a[i], w[j], acc[i][j]);
    }
    __syncthreads();
  }

  #pragma unroll
  for (int i = 0; i < 8; ++i) {
    const int r = tr + i;
    if (r < rows) {
      unsigned short* hwp = hw + (size_t)(n0 + r) * 128;
      ushort4 o0, o1;
      o0.x = f2bf(acc[i][0]); o0.y = f2bf(acc[i][1]);
      o0.z = f2bf(acc[i][2]); o0.w = f2bf(acc[i][3]);
      o1.x = f2bf(acc[i][4]); o1.y = f2bf(acc[i][5]);
      o1.z = f2bf(acc[i][6]); o1.w = f2bf(acc[i][7]);
      *(ushort4*)(hwp + tc4) = o0;
      *(ushort4*)(hwp + tc4 + 64) = o1;
    }
  }
}

// ---- mega0: [gemm1 lower half | degree count] (gemm blocks first) ---------
__global__ __launch_bounds__(256, 2) void k_mega0(
    const float* __restrict__ x, const float* __restrict__ W1,
    unsigned short* __restrict__ hw, int N, int gb,
    const int* __restrict__ coli, int E, int* __restrict__ degi) {
  __shared__ __align__(16) float hsT[32][128];
  __shared__ __align__(16) float Ws[32][128];
  if ((int)blockIdx.x < gb) {
    gemm128_f32(x, 128, W1, hw, N, blockIdx.x * 128, hsT, Ws);
  } else {
    const int b = blockIdx.x - gb;
    #pragma unroll
    for (int h = 0; h < 2; ++h) {
      const int base = b * 2048 + h * 1024 + (int)threadIdx.x * 4;
      if (base + 3 < E) {
        const int4 c4 = *(const int4*)(coli + base);
        atomicAdd(&degi[c4.x], 1); atomicAdd(&degi[c4.y], 1);
        atomicAdd(&degi[c4.z], 1); atomicAdd(&degi[c4.w], 1);
      } else {
        for (int e = base; e < E; ++e) atomicAdd(&degi[coli[e]], 1);
      }
    }
  }
}

// ---- mega1: [gemm1 upper half | CSR fill] (gemm blocks first) -------------
__global__ __launch_bounds__(256, 2) void k_mega1(
    const float* __restrict__ x, const float* __restrict__ W1,
    unsigned short* __restrict__ hw, int N, int gb, int goff,
    const int* __restrict__ rowi, const int* __restrict__ coli,
    int* __restrict__ cursor, int* __restrict__ sorted_row, int E) {
  __shared__ __align__(16) float hsT[32][128];
  __shared__ __align__(16) float Ws[32][128];
  if ((int)blockIdx.x < gb) {
    gemm128_f32(x, 128, W1, hw, N, (goff + blockIdx.x) * 128, hsT, Ws);
  } else {
    const int b = blockIdx.x - gb;
    const int base = b * 1024 + (int)threadIdx.x * 4;
    if (base + 3 < E) {
      const int4 c4 = *(const int4*)(coli + base);
      const int4 r4 = *(const int4*)(rowi + base);
      int p;
      p = atomicAdd(&cursor[c4.x], 1); __builtin_nontemporal_store(r4.x, &sorted_row[p]);
      p = atomicAdd(&cursor[c4.y], 1); __builtin_nontemporal_store(r4.y, &sorted_row[p]);
      p = atomicAdd(&cursor[c4.z], 1); __builtin_nontemporal_store(r4.z, &sorted_row[p]);
      p = atomicAdd(&cursor[c4.w], 1); __builtin_nontemporal_store(r4.w, &sorted_row[p]);
    } else {
      for (int e = base; e < E; ++e) {
        const int p = atomicAdd(&cursor[coli[e]], 1);
        __builtin_nontemporal_store(rowi[e], &sorted_row[p]);
      }
    }
  }
}

// ---- scan pass 1: per-1024-chunk exclusive scan + block sums + dinv -------
__global__ __launch_bounds__(256) void k_scan1(const int* __restrict__ degi, int N,
                                               int* __restrict__ offs,
                                               int* __restrict__ bsums,
                                               float* __restrict__ dinv) {
  __shared__ int sm[256];
  const int b = blockIdx.x, t = threadIdx.x;
  const int base = b * 1024 + t * 4;
  int v[4];
  #pragma unroll
  for (int i = 0; i < 4; ++i) v[i] = (base + i < N) ? degi[base + i] : 0;
  #pragma unroll
  for (int i = 0; i < 4; ++i)
    if (base + i < N) dinv[base + i] = rsqrtf(1.0f + (float)v[i]);
  const int s = v[0] + v[1] + v[2] + v[3];
  sm[t] = s;
  __syncthreads();
  for (int ofs = 1; ofs < 256; ofs <<= 1) {
    const int add = (t >= ofs) ? sm[t - ofs] : 0;
    __syncthreads();
    sm[t] += add;
    __syncthreads();
  }
  if (t == 255) bsums[b] = sm[255];
  int run = sm[t] - s;
  #pragma unroll
  for (int i = 0; i < 4; ++i) {
    if (base + i < N) offs[base + i] = run;
    run += v[i];
  }
}

// ---- scan pass 2: exclusive scan of block sums (nb <= 128) ----------------
__global__ __launch_bounds__(128) void k_scan2(int* __restrict__ bsums, int nb) {
  __shared__ int sm[128];
  const int t = threadIdx.x;
  const int v = (t < nb) ? bsums[t] : 0;
  sm[t] = v;
  __syncthreads();
  for (int ofs = 1; ofs < 128; ofs <<= 1) {
    const int add = (t >= ofs) ? sm[t - ofs] : 0;
    __syncthreads();
    sm[t] += add;
    __syncthreads();
  }
  if (t < nb) bsums[t] = sm[t] - v;
}

// ---- scan pass 3: add block offset; copy to cursor ------------------------
__global__ __launch_bounds__(256) void k_scan3(int* __restrict__ offs,
                                               const int* __restrict__ bsums,
                                               int* __restrict__ cursor, int N) {
  const int add = bsums[blockIdx.x];
  const int base = blockIdx.x * 1024 + threadIdx.x * 4;
  #pragma unroll
  for (int i = 0; i < 4; ++i) {
    const int idx = base + i;
    if (idx < N) {
      const int o = offs[idx] + add;
      offs[idx] = o;
      cursor[idx] = o;
    }
  }
}

// ---- standalone layer GEMM (layers 2,3; bf16 A) ---------------------------
__global__ __launch_bounds__(256, 2) void k_gemm128(
    const unsigned short* __restrict__ A, long long lda,
    const float* __restrict__ W, unsigned short* __restrict__ hw, int N) {
  __shared__ __align__(16) float hsT[32][128];
  __shared__ __align__(16) float Ws[32][128];
  gemm128_bf16(A, lda, W, hw, N, blockIdx.x * 128, hsT, Ws);
}

// ---- segment aggregate (32 lanes/node, ushort4/lane, 8-deep gather) -------
//   hcat[n] = bf16(relu(dinv_n*(dinv_n*hw[n] + sum_in dinv_r*hw[r]) + b))
__global__ __launch_bounds__(256) void k_agg(
    const int* __restrict__ offs, const int* __restrict__ degi,
    const int* __restrict__ sorted_row, const float* __restrict__ dinv,
    const unsigned short* __restrict__ hw, const float* __restrict__ bias,
    unsigned short* __restrict__ hcat, int koff, int N) {
  const int g = (int)((blockIdx.x * 256 + threadIdx.x) >> 5);
  if (g >= N) return;
  const int j = (threadIdx.x & 31) << 2;  // 4 features per lane
  const float dc = dinv[g];
  float acc[4];
  {
    const uint2 sv = *(const uint2*)(hw + (size_t)g * 128 + j);
    float f[4];
    bf4_unpack(sv, f);
    #pragma unroll
    for (int q = 0; q < 4; ++q) acc[q] = dc * f[q];
  }

  const int off = offs[g];
  const int end = off + degi[g];
  int e = off;
  for (; e + 7 < end; e += 8) {  // 8 row-gathers in flight
    int r[8];
    #pragma unroll
    for (int t = 0; t < 8; ++t) r[t] = sorted_row[e + t];
    float dr[8];
    uint2 v[8];
    #pragma unroll
    for (int t = 0; t < 8; ++t) {
      dr[t] = dinv[r[t]];
      v[t] = *(const uint2*)(hw + (size_t)r[t] * 128 + j);
    }
    #pragma unroll
    for (int t = 0; t < 8; ++t) {
      float f[4];
      bf4_unpack(v[t], f);
      #pragma unroll
      for (int q = 0; q < 4; ++q) acc[q] = fmaf(dr[t], f[q], acc[q]);
    }
  }
  for (; e + 3 < end; e += 4) {
    int r[4];
    #pragma unroll
    for (int t = 0; t < 4; ++t) r[t] = sorted_row[e + t];
    float dr[4];
    uint2 v[4];
    #pragma unroll
    for (int t = 0; t < 4; ++t) {
      dr[t] = dinv[r[t]];
      v[t] = *(const uint2*)(hw + (size_t)r[t] * 128 + j);
    }
    #pragma unroll
    for (int t = 0; t < 4; ++t) {
      float f[4];
      bf4_unpack(v[t], f);
      #pragma unroll
      for (int q = 0; q < 4; ++q) acc[q] = fmaf(dr[t], f[q], acc[q]);
    }
  }
  for (; e < end; ++e) {
    const int r0 = sorted_row[e];
    const float d0 = dinv[r0];
    const uint2 v0 = *(const uint2*)(hw + (size_t)r0 * 128 + j);
    float f[4];
    bf4_unpack(v0, f);
    #pragma unroll
    for (int q = 0; q < 4; ++q) acc[q] = fmaf(d0, f[q], acc[q]);
  }

  const float4 bb = *(const float4*)(bias + j);
  const float o0 = fmaxf(fmaf(dc, acc[0], bb.x), 0.f);
  const float o1 = fmaxf(fmaf(dc, acc[1], bb.y), 0.f);
  const float o2 = fmaxf(fmaf(dc, acc[2], bb.z), 0.f);
  const float o3 = fmaxf(fmaf(dc, acc[3], bb.w), 0.f);
  uint2 st;
  st.x = bfpack(o0, o1);
  st.y = bfpack(o2, o3);
  *(uint2*)(hcat + (size_t)g * 384 + koff + j) = st;
}

// ---- final: out = hcat(bf16) @ Wlin + blin, K=384, 12 chunks of 32 --------
__global__ __launch_bounds__(256, 2) void k_final(
    const unsigned short* __restrict__ hcat, const float* __restrict__ Wlin,
    const float* __restrict__ blin, float* __restrict__ out, int N) {
  __shared__ __align__(16) float hsT[32][128];  // 16KB
  __shared__ __align__(16) float Ws[32][64];    // 8KB
  const int tid = threadIdx.x;
  const int n0 = blockIdx.x * 128;
  const int rows = min(128, N - n0);
  const int tc = (tid & 15) << 2;
  const int tr = (tid >> 4) << 3;
  float acc[8][4] = {};
  uint4 pa[2];

  auto loadA = [&](int kc) {
    #pragma unroll
    for (int u = 0; u < 2; ++u) {
      const int i = tid + 256 * u;
      const int r = i >> 2, k8 = (i & 3) << 3;
      uint4 v = make_uint4(0u, 0u, 0u, 0u);
      if (r < rows) v = *(const uint4*)(hcat + (size_t)(n0 + r) * 384 + kc + k8);
      pa[u] = v;
    }
  };
  auto stageA = [&]() {
    #pragma unroll
    for (int u = 0; u < 2; ++u) {
      const int i = tid + 256 * u;
      const int r = i >> 2, k8 = (i & 3) << 3;
      float f[8];
      bf8_unpack(pa[u], f);
      #pragma unroll
      for (int t = 0; t < 4; ++t) {
        const int k = k8 + 2 * t;
        const int c = r ^ (k & 28);
        hsT[k][c] = f[2 * t];
        hsT[k + 1][c] = f[2 * t + 1];
      }
    }
  };
  auto stageW = [&](int kc) {
    #pragma unroll
    for (int u = 0; u < 2; ++u) {
      const int i = tid + 256 * u;
      const int k = i >> 4, c = (i & 15) << 2;
      *(float4*)&Ws[k][c] = *(const float4*)(Wlin + (size_t)(kc + k) * 64 + c);
    }
  };

  loadA(0);
  for (int kc = 0; kc < 384; kc += 32) {
    stageW(kc);
    stageA();
    __syncthreads();
    if (kc + 32 < 384) loadA(kc + 32);
    #pragma unroll
    for (int k = 0; k < 32; ++k) {
      const int s = k & 28;
      const float4 a0 = *(const float4*)&hsT[k][tr ^ s];
      const float4 a1 = *(const float4*)&hsT[k][(tr + 4) ^ s];
      const float4 w0 = *(const float4*)&Ws[k][tc];
      const float a[8] = {a0.x, a0.y, a0.z, a0.w, a1.x, a1.y, a1.z, a1.w};
      const float w[4] = {w0.x, w0.y, w0.z, w0.w};
      #pragma unroll
      for (int i = 0; i < 8; ++i)
        #pragma unroll
        for (int j = 0; j < 4; ++j) acc[i][j] = fmaf(a[i], w[j], acc[i][j]);
    }
    __syncthreads();
  }

  #pragma unroll
  for (int i = 0; i < 8; ++i) {
    const int r = tr + i;
    if (r < rows) {
      const float4 bb = *(const float4*)(blin + tc);
      *(float4*)(out + (size_t)(n0 + r) * 64 + tc) =
          make_float4(acc[i][0] + bb.x, acc[i][1] + bb.y,
                      acc[i][2] + bb.z, acc[i][3] + bb.w);
    }
  }
}

extern "C" void kernel_launch(void* const* d_in, const int* in_sizes, int n_in,
                              void* d_out, int out_size, void* d_ws, size_t ws_size,
                              hipStream_t stream) {
  const float* x    = (const float*)d_in[0];
  const int*   ei   = (const int*)d_in[1];
  const float* W1   = (const float*)d_in[2];
  const float* b1   = (const float*)d_in[3];
  const float* W2   = (const float*)d_in[4];
  const float* b2   = (const float*)d_in[5];
  const float* W3   = (const float*)d_in[6];
  const float* b3   = (const float*)d_in[7];
  const float* Wlin = (const float*)d_in[8];
  const float* blin = (const float*)d_in[9];

  const int N = in_sizes[0] / 128;
  const int E = in_sizes[1] / 2;
  const int* rowi = ei;
  const int* coli = ei + E;

  // ws: degi | dinv | offs | cursor | bsums | sorted_row | hw(bf16) | hcat(bf16)
  char* ws = (char*)d_ws;
  const size_t nb4 = (((size_t)N * 4) + 255) & ~(size_t)255;
  int*   degi       = (int*)ws;                 ws += nb4;
  float* dinv       = (float*)ws;               ws += nb4;
  int*   offs       = (int*)ws;                 ws += nb4;
  int*   cursor     = (int*)ws;                 ws += nb4;
  int*   bsums      = (int*)ws;                 ws += 1024;
  int*   sorted_row = (int*)ws;                 ws += (((size_t)E * 4) + 255) & ~(size_t)255;
  unsigned short* hw   = (unsigned short*)ws;   ws += (size_t)N * 128 * 2;
  unsigned short* hcat = (unsigned short*)ws;

  const int nblk = (N + 1023) / 1024;  // <= 128 for N <= 131072
  const int gemmBlocks = (N + 127) / 128;
  const int gb0 = gemmBlocks / 2;          // gemm1 lower half (mega0)
  const int gb1 = gemmBlocks - gb0;        // gemm1 upper half (mega1)
  const int degBlocks  = (E + 2047) / 2048;
  const int fillBlocks = (E + 1023) / 1024;
  const int aggBlocks  = (N + 7) / 8;

  hipMemsetAsync(degi, 0, (size_t)N * 4, stream);
  k_mega0<<<gb0 + degBlocks, 256, 0, stream>>>(x, W1, hw, N, gb0, coli, E, degi);
  k_scan1<<<nblk, 256, 0, stream>>>(degi, N, offs, bsums, dinv);
  k_scan2<<<1, 128, 0, stream>>>(bsums, nblk);
  k_scan3<<<nblk, 256, 0, stream>>>(offs, bsums, cursor, N);
  k_mega1<<<gb1 + fillBlocks, 256, 0, stream>>>(x, W1, hw, N, gb1, gb0,
                                                rowi, coli, cursor, sorted_row, E);

  k_agg<<<aggBlocks, 256, 0, stream>>>(offs, degi, sorted_row, dinv, hw,
                                       b1, hcat, 0, N);
  k_gemm128<<<gemmBlocks, 256, 0, stream>>>(hcat, 384, W2, hw, N);
  k_agg<<<aggBlocks, 256, 0, stream>>>(offs, degi, sorted_row, dinv, hw,
                                       b2, hcat, 128, N);
  k_gemm128<<<gemmBlocks, 256, 0, stream>>>(hcat + 128, 384, W3, hw, N);
  k_agg<<<aggBlocks, 256, 0, stream>>>(offs, degi, sorted_row, dinv, hw,
                                       b3, hcat, 256, N);
  k_final<<<gemmBlocks, 256, 0, stream>>>(hcat, Wlin, blin, (float*)d_out, N);
}